// Round 11
// baseline (94.068 us; speedup 1.0000x reference)
//
#include <hip/hip_runtime.h>

#define BQ 32
#define H  128
#define C  512
#define D  128

typedef _Float16 half8v __attribute__((ext_vector_type(8)));
typedef float floatx4 __attribute__((ext_vector_type(4)));

// ---------------------------------------------------------------------------
// Kernel 0: Q fp32 -> fp16 fragments for 16x16x32 MFMA B-operand, plus zero
// the loss accumulator (d_out).
// Frag index (half8 units): ((b*4 + kb)*2 + sh)*64 + lane
//   elem[n = lane&15][k = kb*32 + (lane>>4)*8 + j],  s = sh*16 + n
// ---------------------------------------------------------------------------
__global__ __launch_bounds__(256) void qprep_kernel(const float* __restrict__ q,
                                                    _Float16* __restrict__ qs,
                                                    float* __restrict__ out) {
  int t = blockIdx.x * 256 + threadIdx.x;     // 0..16383, one half8 frag each
  if (t == 0) out[0] = 0.0f;
  int lane = t & 63;
  int sh   = (t >> 6) & 1;
  int kb   = (t >> 7) & 3;
  int b    = t >> 9;
  int s    = sh * 16 + (lane & 15);
  int h    = kb * 32 + (lane >> 4) * 8;
  const float* src = q + ((b * 32 + s) * H + h);
  float4 v0 = *(const float4*)src;
  float4 v1 = *(const float4*)(src + 4);
  half8v o = { (_Float16)v0.x, (_Float16)v0.y, (_Float16)v0.z, (_Float16)v0.w,
               (_Float16)v1.x, (_Float16)v1.y, (_Float16)v1.z, (_Float16)v1.w };
  *(half8v*)(qs + (size_t)t * 8) = o;
}

// ---------------------------------------------------------------------------
// Kernel 1: block c (256 thr, 4 waves) -> scores[b][c].  [r10 base]
// 16x16x32 f16 MFMA, transposed: A = P_c (m = d), B = Q_b (n = s).
// Wave w: d-half dq=w&1 (64 rows = 4 m-tiles), s-half sh=w>>1 (16 cols).
// Changes vs r10: (1) prefetch distance 3 (qb 4-ring, &3 indexing);
// (2) shuffle-free in-loop reduction: 15 in-lane v_max + ONE unconditional
// ds_write_b32 (pmm[b][w][nrow*4+quad]: 64 distinct addrs, 2 lanes/bank =
// conflict-free); quad/dq combine deferred to the one-time epilogue as
// float4 LDS reads. Steady-state loop has zero cross-lane dependencies.
// ---------------------------------------------------------------------------
__global__ __launch_bounds__(256, 2) void scores_kernel(const float* __restrict__ pos,
                                                        const _Float16* __restrict__ qs,
                                                        float* __restrict__ scores) {
  const int c    = blockIdx.x;
  const int tid  = threadIdx.x;
  const int w    = tid >> 6;
  const int lane = tid & 63;
  const int dq   = w & 1;            // d-half
  const int sh   = w >> 1;           // s-half
  const int quad = lane >> 4;
  const int nrow = lane & 15;

  __shared__ float pmm[BQ][4][64];   // [b][wave][nrow*4+quad]  32 KB

  const half8v* qf = (const half8v*)qs;
  const float*  pc = pos + (size_t)c * (D * H);

  half8v  pa[4][4];    // P_c A-frags [mt][kb]  (64 VGPRs)
  half8v  qb[4][4];    // Q B-frags, 4-ring, prefetch distance 3 (64 VGPRs)
  floatx4 acc[2][4];   // [buf][mt] (32 VGPRs)
  floatx4 zc = {0.f, 0.f, 0.f, 0.f};   // persistent zero C-operand

  // P_c A-frags: A[m = dq*64 + mt*16 + nrow][k = kb*32 + quad*8 + j]
#pragma unroll
  for (int kb = 0; kb < 4; ++kb)
#pragma unroll
    for (int mt = 0; mt < 4; ++mt) {
      const float* src = pc + ((dq * 64 + mt * 16 + nrow) * H + kb * 32 + quad * 8);
      float4 v0 = *(const float4*)src;
      float4 v1 = *(const float4*)(src + 4);
      half8v f = { (_Float16)v0.x, (_Float16)v0.y, (_Float16)v0.z, (_Float16)v0.w,
                   (_Float16)v1.x, (_Float16)v1.y, (_Float16)v1.z, (_Float16)v1.w };
      pa[mt][kb] = f;
    }

  // prime prefetch ring to depth 3 (b = 0,1,2)
#pragma unroll
  for (int pb = 0; pb < 3; ++pb)
#pragma unroll
    for (int kb = 0; kb < 4; ++kb)
      qb[pb][kb] = qf[((pb * 4 + kb) * 2 + sh) * 64 + lane];

  // Reduce: in-lane max over this lane's 16 of the wave's 64 d-rows, then one
  // conflict-free ds_write; cross-quad/cross-dq max deferred to epilogue.
  // C/D: col s_local = lane&15, row d_local = quad*4 + r  [m89/m91]
  auto reduce_store = [&](int b, floatx4 (&a)[4]) {
    float m0 = fmaxf(fmaxf(a[0][0], a[0][1]), fmaxf(a[0][2], a[0][3]));
    float m1 = fmaxf(fmaxf(a[1][0], a[1][1]), fmaxf(a[1][2], a[1][3]));
    float m2 = fmaxf(fmaxf(a[2][0], a[2][1]), fmaxf(a[2][2], a[2][3]));
    float m3 = fmaxf(fmaxf(a[3][0], a[3][1]), fmaxf(a[3][2], a[3][3]));
    pmm[b][w][nrow * 4 + quad] = fmaxf(fmaxf(m0, m1), fmaxf(m2, m3));
  };

  // main loop: prefetch b+3, compute b, reduce b-1
#pragma unroll
  for (int b = 0; b < BQ; ++b) {
    const int cur = b & 1;
    if (b + 3 < BQ) {
      half8v* dst = qb[(b + 3) & 3];
#pragma unroll
      for (int kb = 0; kb < 4; ++kb)
        dst[kb] = qf[(((b + 3) * 4 + kb) * 2 + sh) * 64 + lane];
    }
    const half8v* qc = qb[b & 3];
#pragma unroll
    for (int mt = 0; mt < 4; ++mt)
      acc[cur][mt] = __builtin_amdgcn_mfma_f32_16x16x32_f16(pa[mt][0], qc[0], zc, 0, 0, 0);
#pragma unroll
    for (int kb = 1; kb < 4; ++kb)
#pragma unroll
      for (int mt = 0; mt < 4; ++mt)
        acc[cur][mt] = __builtin_amdgcn_mfma_f32_16x16x32_f16(pa[mt][kb], qc[kb], acc[cur][mt], 0, 0, 0);
    if (b > 0) reduce_store(b - 1, acc[cur ^ 1]);
  }
  reduce_store(BQ - 1, acc[1]);   // b=31 landed in acc[1]

  __syncthreads();

  // epilogue: scores[b][c] = 50 * sum_s max over (2 dq-waves x 4 quads)
  // s in [0,16): waves 0,1 (sh=0); s in [16,32): waves 2,3 (sh=1).
  // pmm[b][w][sl*4..sl*4+3] is a float4 of the 4 quad-partials.
  {
    int b  = tid >> 3;
    int t8 = tid & 7;
    float v = 0.f;
#pragma unroll
    for (int j = 0; j < 4; ++j) {
      int s  = t8 * 4 + j;
      int h2 = s >> 4, sl = s & 15;
      float4 x = *(float4*)&pmm[b][2 * h2][sl * 4];
      float4 y = *(float4*)&pmm[b][2 * h2 + 1][sl * 4];
      float m = fmaxf(fmaxf(fmaxf(x.x, x.y), fmaxf(x.z, x.w)),
                      fmaxf(fmaxf(y.x, y.y), fmaxf(y.z, y.w)));
      v += m;
    }
    v += __shfl_xor(v, 1);
    v += __shfl_xor(v, 2);
    v += __shfl_xor(v, 4);
    if (t8 == 0) scores[b * C + c] = v * 50.0f;   // / TEMPERATURE
  }
}

// ---------------------------------------------------------------------------
// Kernel 2: one block per b; loss += (logsumexp_c - scores[b][0]) / 32
// ---------------------------------------------------------------------------
__global__ __launch_bounds__(256) void loss_kernel(const float* __restrict__ scores,
                                                   float* __restrict__ out) {
  __shared__ float red[8];
  const int b = blockIdx.x, tid = threadIdx.x, w = tid >> 6, lane = tid & 63;
  const float* row = scores + b * C;
  float x0 = row[tid], x1 = row[tid + 256];
  float mx = fmaxf(x0, x1);
#pragma unroll
  for (int off = 1; off < 64; off <<= 1) mx = fmaxf(mx, __shfl_xor(mx, off));
  if (lane == 0) red[w] = mx;
  __syncthreads();
  float bmax = fmaxf(fmaxf(red[0], red[1]), fmaxf(red[2], red[3]));
  float e = __expf(x0 - bmax) + __expf(x1 - bmax);
#pragma unroll
  for (int off = 1; off < 64; off <<= 1) e += __shfl_xor(e, off);
  if (lane == 0) red[4 + w] = e;
  __syncthreads();
  if (tid == 0) {
    float s = red[4] + red[5] + red[6] + red[7];
    atomicAdd(out, (bmax + __logf(s) - row[0]) * (1.0f / 32.0f));
  }
}

extern "C" void kernel_launch(void* const* d_in, const int* in_sizes, int n_in,
                              void* d_out, int out_size, void* d_ws, size_t ws_size,
                              hipStream_t stream) {
  const float* q = (const float*)d_in[0];   // [32,32,128] fp32
  const float* p = (const float*)d_in[1];   // [512,128,128] fp32
  float* scores  = (float*)d_ws;                              // 64 KB
  _Float16* qs   = (_Float16*)((char*)d_ws + 65536);          // 256 KB fp16 frags

  qprep_kernel<<<64, 256, 0, stream>>>(q, qs, (float*)d_out);
  scores_kernel<<<C, 256, 0, stream>>>(p, qs, scores);
  loss_kernel<<<32, 256, 0, stream>>>(scores, (float*)d_out);
}